// Round 3
// baseline (780.737 us; speedup 1.0000x reference)
//
#include <hip/hip_runtime.h>
#include <math.h>

#define NLAT 361
#define NLON 720
#define EPSF 1e-7f
#define T0 (6.283185307179586 / 720.0)   // 2*pi/720

// ---------------------------------------------------------------------------
// Kernel 1: real DFT over longitude. One wave (64 thr) per block, one block
// per (bc, latitude-pair). Each thread owns THREE m-values {t, t+64, t+128}
// so the 4 broadcast ds_read_b128 per iteration feed 48 accumulator FMAs
// (3x better LDS:VALU ratio than one-m-per-thread) and rotator twiddle work
// is amortized. Rotators replace any twiddle table.
// Output: GG[m][j][bc] = float4(Fp.re, Fp.im, Ft.re, Ft.im) * (2pi/720)*w[j],
// m = 0..359 (Nyquist bin dead under the triangular mask downstream).
// ---------------------------------------------------------------------------
__global__ void dft_kernel(const float* __restrict__ pred,
                           const float* __restrict__ targ,
                           const float* __restrict__ wq,
                           float4* __restrict__ GG) {
  const int blk = blockIdx.x;          // 16 * 181 blocks
  const int bc  = blk / 181;
  const int p   = blk - bc * 181;
  const int j0  = 2 * p;
  const int j1  = (j0 + 1 <= 360) ? j0 + 1 : j0;   // row 360 self-pairs

  const float* fp0 = pred + ((size_t)bc * NLAT + j0) * NLON;
  const float* ft0 = targ + ((size_t)bc * NLAT + j0) * NLON;
  const float* fp1 = pred + ((size_t)bc * NLAT + j1) * NLON;
  const float* ft1 = targ + ((size_t)bc * NLAT + j1) * NLON;

  __shared__ float4 eo[2][360];        // (e_p, o_p, e_t, o_t), n = 1..359
  const int t = threadIdx.x;
  for (int idx = t; idx < 720; idx += 64) {
    int r = idx / 360, n = idx - 360 * r;
    if (n >= 1) {
      const float* a = r ? fp1 : fp0;
      const float* b = r ? ft1 : ft0;
      float a1 = a[n], a2 = a[NLON - n], b1 = b[n], b2 = b[NLON - n];
      eo[r][n] = make_float4(a1 + a2, a1 - a2, b1 + b2, b1 - b2);
    }
  }
  __syncthreads();

  // 3 m-slots per thread
  float c1[3], s1[3], c2[3], s2[3], cv[3], sv[3];
#pragma unroll
  for (int s = 0; s < 3; ++s) {
    int m = t + 64 * s;
    float a1 = (float)(T0 * (double)m);
    float a2 = (float)(T0 * (double)(2 * m));
    sincosf(a1, &s1[s], &c1[s]);
    sincosf(a2, &sv[s], &cv[s]);
    c2[s] = cv[s]; s2[s] = sv[s];
  }

  float CoP[3][2], SoP[3][2], CeP[3][2], SeP[3][2];
  float CoT[3][2], SoT[3][2], CeT[3][2], SeT[3][2];
#pragma unroll
  for (int s = 0; s < 3; ++s)
#pragma unroll
    for (int r = 0; r < 2; ++r) {
      CoP[s][r] = SoP[s][r] = CeP[s][r] = SeP[s][r] = 0.f;
      CoT[s][r] = SoT[s][r] = CeT[s][r] = SeT[s][r] = 0.f;
    }

  for (int k = 1; k <= 179; ++k) {
    float4 u0 = eo[0][2 * k - 1], v0 = eo[0][2 * k];
    float4 u1 = eo[1][2 * k - 1], v1 = eo[1][2 * k];
#pragma unroll
    for (int s = 0; s < 3; ++s) {
      CoP[s][0] = fmaf(u0.x, c1[s], CoP[s][0]);
      SoP[s][0] = fmaf(u0.y, s1[s], SoP[s][0]);
      CoT[s][0] = fmaf(u0.z, c1[s], CoT[s][0]);
      SoT[s][0] = fmaf(u0.w, s1[s], SoT[s][0]);
      CeP[s][0] = fmaf(v0.x, c2[s], CeP[s][0]);
      SeP[s][0] = fmaf(v0.y, s2[s], SeP[s][0]);
      CeT[s][0] = fmaf(v0.z, c2[s], CeT[s][0]);
      SeT[s][0] = fmaf(v0.w, s2[s], SeT[s][0]);
      CoP[s][1] = fmaf(u1.x, c1[s], CoP[s][1]);
      SoP[s][1] = fmaf(u1.y, s1[s], SoP[s][1]);
      CoT[s][1] = fmaf(u1.z, c1[s], CoT[s][1]);
      SoT[s][1] = fmaf(u1.w, s1[s], SoT[s][1]);
      CeP[s][1] = fmaf(v1.x, c2[s], CeP[s][1]);
      SeP[s][1] = fmaf(v1.y, s2[s], SeP[s][1]);
      CeT[s][1] = fmaf(v1.z, c2[s], CeT[s][1]);
      SeT[s][1] = fmaf(v1.w, s2[s], SeT[s][1]);
      float nc1 = fmaf(c1[s], cv[s], -(s1[s] * sv[s]));
      float ns1 = fmaf(s1[s], cv[s],  (c1[s] * sv[s]));
      c1[s] = nc1; s1[s] = ns1;
      float nc2 = fmaf(c2[s], cv[s], -(s2[s] * sv[s]));
      float ns2 = fmaf(s2[s], cv[s],  (c2[s] * sv[s]));
      c2[s] = nc2; s2[s] = ns2;
    }
  }
  { // tail n = 359 (odd); c1,s1 now at angle 359*m*t0
    float4 u0 = eo[0][359], u1 = eo[1][359];
#pragma unroll
    for (int s = 0; s < 3; ++s) {
      CoP[s][0] = fmaf(u0.x, c1[s], CoP[s][0]);
      SoP[s][0] = fmaf(u0.y, s1[s], SoP[s][0]);
      CoT[s][0] = fmaf(u0.z, c1[s], CoT[s][0]);
      SoT[s][0] = fmaf(u0.w, s1[s], SoT[s][0]);
      CoP[s][1] = fmaf(u1.x, c1[s], CoP[s][1]);
      SoP[s][1] = fmaf(u1.y, s1[s], SoP[s][1]);
      CoT[s][1] = fmaf(u1.z, c1[s], CoT[s][1]);
      SoT[s][1] = fmaf(u1.w, s1[s], SoT[s][1]);
    }
  }

  const float sgn = (t & 1) ? -1.f : 1.f;   // parity of m (slots differ by 64)
  const float t0w = (float)T0;
  const float baseP0 = fp0[0] + sgn * fp0[360];
  const float baseT0 = ft0[0] + sgn * ft0[360];
  const float baseP1 = fp1[0] + sgn * fp1[360];
  const float baseT1 = ft1[0] + sgn * ft1[360];
  const float sc0 = t0w * wq[j0];
  const float sc1 = t0w * wq[j1];

#pragma unroll
  for (int s = 0; s < 3; ++s) {
    const int m = t + 64 * s;
    if (m > 180) continue;
    // row 0, bin m
    {
      float reP = baseP0 + CeP[s][0] + CoP[s][0], imP = -(SeP[s][0] + SoP[s][0]);
      float reT = baseT0 + CeT[s][0] + CoT[s][0], imT = -(SeT[s][0] + SoT[s][0]);
      GG[((size_t)m * NLAT + j0) * 16 + bc] =
          make_float4(reP * sc0, imP * sc0, reT * sc0, imT * sc0);
    }
    // row 1, bin m (j1==j0 duplicate write is same-thread same-value: benign)
    {
      float reP = baseP1 + CeP[s][1] + CoP[s][1], imP = -(SeP[s][1] + SoP[s][1]);
      float reT = baseT1 + CeT[s][1] + CoT[s][1], imT = -(SeT[s][1] + SoT[s][1]);
      GG[((size_t)m * NLAT + j1) * 16 + bc] =
          make_float4(reP * sc1, imP * sc1, reT * sc1, imT * sc1);
    }
    if (m >= 1 && m <= 179) {
      int m2 = 360 - m;
      float reP = baseP0 + CeP[s][0] - CoP[s][0], imP = SeP[s][0] - SoP[s][0];
      float reT = baseT0 + CeT[s][0] - CoT[s][0], imT = SeT[s][0] - SoT[s][0];
      GG[((size_t)m2 * NLAT + j0) * 16 + bc] =
          make_float4(reP * sc0, imP * sc0, reT * sc0, imT * sc0);
      float reP1 = baseP1 + CeP[s][1] - CoP[s][1], imP1 = SeP[s][1] - SoP[s][1];
      float reT1 = baseT1 + CeT[s][1] - CoT[s][1], imT1 = SeT[s][1] - SoT[s][1];
      GG[((size_t)m2 * NLAT + j1) * 16 + bc] =
          make_float4(reP1 * sc1, imP1 * sc1, reT1 * sc1, imT1 * sc1);
    }
  }
}

// ---------------------------------------------------------------------------
// Kernel 2: Legendre contraction + triangular PSD/cross-spectrum with the
// parity fold Pbar_lm(-x) = (-1)^(l+m) Pbar_lm(x) (reads only j<=180 of leg).
// Thread map (256 thr): bc = tid&15 (LOW bits -> 256B-contiguous wave loads),
// jl = (tid>>4)&3 (intra-wave, shuffle-reducible), lsel = tid>>6 (wave-
// uniform l-group -> LDS b128 read is a 16-way broadcast, conflict-free).
// Tile: 16 l-rows x 2 m per block; grid = 2204 triangular blocks (8.6/CU).
// Depth-1 software prefetch on the GG loads.
// ---------------------------------------------------------------------------
__global__ void leg_kernel(const float* __restrict__ leg,
                           const float4* __restrict__ GG,
                           float* __restrict__ S) {
  int bid = blockIdx.x;
  int lt = 0, acc = 0;
  for (;;) {
    int cnt = (lt < 22) ? 8 * (lt + 1) : 180;
    if (bid < acc + cnt) break;
    acc += cnt; ++lt;
  }
  const int l0 = 16 * lt;
  const int m0 = 2 * (bid - acc);

  __shared__ float sLg[181][20];   // transposed tile; lsel wave-uniform =>
                                   // 4 distinct b128 addrs/wave, banks disjoint
  const int tid  = threadIdx.x;
  const int bc   = tid & 15;
  const int jl   = (tid >> 4) & 3;
  const int lsel = tid >> 6;       // 0..3, uniform within a wave

  float racc[4][4];
#pragma unroll
  for (int r = 0; r < 4; ++r)
#pragma unroll
    for (int c = 0; c < 4; ++c) racc[r][c] = 0.f;

#pragma unroll 1
  for (int mi = 0; mi < 2; ++mi) {
    const int m = m0 + mi;
    if (mi) __syncthreads();
    for (int idx = tid; idx < 16 * 181; idx += 256) {
      int lp = idx / 181, j = idx - lp * 181;
      int l = l0 + lp;
      sLg[j][lp] = (l <= 360) ? leg[((size_t)l * NLAT + m) * NLAT + j] : 0.f;
    }
    __syncthreads();

    const float sgn  = ((l0 + m) & 1) ? -1.f : 1.f;
    const float msgn = -sgn;
    float ca[4][4];
#pragma unroll
    for (int r = 0; r < 4; ++r)
#pragma unroll
      for (int c = 0; c < 4; ++c) ca[r][c] = 0.f;

    const float4* gm = GG + (size_t)m * (NLAT * 16);
    float4 A = gm[(size_t)jl * 16 + bc];
    float4 B = gm[(size_t)(360 - jl) * 16 + bc];
#pragma unroll 1
    for (int j = jl; j < 180; j += 4) {
      int jn = j + 4;                               // <= 183: in-row, safe
      float4 An = gm[(size_t)jn * 16 + bc];
      float4 Bn = gm[(size_t)(360 - jn) * 16 + bc];
      float u0x = fmaf(sgn,  B.x, A.x), u0y = fmaf(sgn,  B.y, A.y);
      float u0z = fmaf(sgn,  B.z, A.z), u0w = fmaf(sgn,  B.w, A.w);
      float u1x = fmaf(msgn, B.x, A.x), u1y = fmaf(msgn, B.y, A.y);
      float u1z = fmaf(msgn, B.z, A.z), u1w = fmaf(msgn, B.w, A.w);
      float4 lg = *(const float4*)&sLg[j][lsel * 4];
      ca[0][0] = fmaf(lg.x, u0x, ca[0][0]); ca[0][1] = fmaf(lg.x, u0y, ca[0][1]);
      ca[0][2] = fmaf(lg.x, u0z, ca[0][2]); ca[0][3] = fmaf(lg.x, u0w, ca[0][3]);
      ca[1][0] = fmaf(lg.y, u1x, ca[1][0]); ca[1][1] = fmaf(lg.y, u1y, ca[1][1]);
      ca[1][2] = fmaf(lg.y, u1z, ca[1][2]); ca[1][3] = fmaf(lg.y, u1w, ca[1][3]);
      ca[2][0] = fmaf(lg.z, u0x, ca[2][0]); ca[2][1] = fmaf(lg.z, u0y, ca[2][1]);
      ca[2][2] = fmaf(lg.z, u0z, ca[2][2]); ca[2][3] = fmaf(lg.z, u0w, ca[2][3]);
      ca[3][0] = fmaf(lg.w, u1x, ca[3][0]); ca[3][1] = fmaf(lg.w, u1y, ca[3][1]);
      ca[3][2] = fmaf(lg.w, u1z, ca[3][2]); ca[3][3] = fmaf(lg.w, u1w, ca[3][3]);
      A = An; B = Bn;
    }
    if (jl == 0) {   // peeled self-paired center j=180 (A holds gm[180] here)
      float4 lg = *(const float4*)&sLg[180][lsel * 4];
      float u0x, u0y, u0z, u0w, u1x, u1y, u1z, u1w;
      if (sgn > 0.f) {
        u0x = A.x; u0y = A.y; u0z = A.z; u0w = A.w;
        u1x = u1y = u1z = u1w = 0.f;
      } else {
        u0x = u0y = u0z = u0w = 0.f;
        u1x = A.x; u1y = A.y; u1z = A.z; u1w = A.w;
      }
      ca[0][0] = fmaf(lg.x, u0x, ca[0][0]); ca[0][1] = fmaf(lg.x, u0y, ca[0][1]);
      ca[0][2] = fmaf(lg.x, u0z, ca[0][2]); ca[0][3] = fmaf(lg.x, u0w, ca[0][3]);
      ca[1][0] = fmaf(lg.y, u1x, ca[1][0]); ca[1][1] = fmaf(lg.y, u1y, ca[1][1]);
      ca[1][2] = fmaf(lg.y, u1z, ca[1][2]); ca[1][3] = fmaf(lg.y, u1w, ca[1][3]);
      ca[2][0] = fmaf(lg.z, u0x, ca[2][0]); ca[2][1] = fmaf(lg.z, u0y, ca[2][1]);
      ca[2][2] = fmaf(lg.z, u0z, ca[2][2]); ca[2][3] = fmaf(lg.z, u0w, ca[2][3]);
      ca[3][0] = fmaf(lg.w, u1x, ca[3][0]); ca[3][1] = fmaf(lg.w, u1y, ca[3][1]);
      ca[3][2] = fmaf(lg.w, u1z, ca[3][2]); ca[3][3] = fmaf(lg.w, u1w, ca[3][3]);
    }

    // reduce across the 4 jl groups (lane bits 4,5) — butterfly
#pragma unroll
    for (int r = 0; r < 4; ++r)
#pragma unroll
      for (int c = 0; c < 4; ++c) {
        ca[r][c] += __shfl_xor(ca[r][c], 16);
        ca[r][c] += __shfl_xor(ca[r][c], 32);
      }
    const float ef = (m == 0) ? 1.f : 2.f;
#pragma unroll
    for (int r = 0; r < 4; ++r) {
      float pr = ca[r][0], pi = ca[r][1], tr = ca[r][2], ti = ca[r][3];
      racc[r][0] += ef * (pr * pr + pi * pi);
      racc[r][1] += ef * (tr * tr + ti * ti);
      racc[r][2] += ef * (pr * tr + pi * ti);
      racc[r][3] += ef * (pr * ti - pi * tr);
    }
  }

  if (jl == 0) {
#pragma unroll
    for (int r = 0; r < 4; ++r) {
      int l = l0 + lsel * 4 + r;
      if (l < 360) {
        float* sp = S + ((size_t)bc * 360 + l) * 4;
        atomicAdd(sp + 0, racc[r][0]);
        atomicAdd(sp + 1, racc[r][1]);
        atomicAdd(sp + 2, racc[r][2]);
        atomicAdd(sp + 3, racc[r][3]);
      }
    }
  }
}

// ---------------------------------------------------------------------------
// Kernel 3: final loss epilogue + reduction. One block.
// ---------------------------------------------------------------------------
__global__ void loss_kernel(const float* __restrict__ S,
                            const float* __restrict__ wts,
                            float* __restrict__ out) {
  const int tid = threadIdx.x;
  float acc = 0.f;
  for (int i = tid; i < 16 * 360; i += 256) {
    int bc = i / 360;
    const float* sp = S + (size_t)i * 4;
    float pp = sp[0] + EPSF;
    float tp = sp[1] + EPSF;
    float sr = sp[2], si = sp[3];
    float mag   = sqrtf(sr * sr + si * si);
    float denom = sqrtf(pp * tp + EPSF);
    float coh   = mag / (denom + EPSF);
    coh = fminf(fmaxf(coh, 0.f), 1.f);
    float sqp = sqrtf(pp), sqt = sqrtf(tp);
    float amp = (sqp - sqt) * (sqp - sqt);
    float dec = 2.f * fmaxf(pp, tp) * (1.f - coh);
    acc += (amp + dec) * wts[bc & 7];
  }
  __shared__ float red[4];
#pragma unroll
  for (int off = 32; off > 0; off >>= 1) acc += __shfl_xor(acc, off, 64);
  if ((tid & 63) == 0) red[tid >> 6] = acc;
  __syncthreads();
  if (tid == 0) {
    float loss = (red[0] + red[1] + red[2] + red[3]) / (360.f * 16.f);
    out[0] = isnan(loss) ? 1e6f : loss;
  }
}

// ---------------------------------------------------------------------------
extern "C" void kernel_launch(void* const* d_in, const int* in_sizes, int n_in,
                              void* d_out, int out_size, void* d_ws, size_t ws_size,
                              hipStream_t stream) {
  const float* pred = (const float*)d_in[0];   // [2,8,361,720]
  const float* targ = (const float*)d_in[1];   // [2,8,361,720]
  const float* wts  = (const float*)d_in[2];   // [8]
  const float* leg  = (const float*)d_in[3];   // [361,361,361]
  const float* wq   = (const float*)d_in[4];   // [361]
  float* out = (float*)d_out;

  float4* GG = (float4*)d_ws;                            // [360][361][16] float4
  float*  S  = (float*)(GG + (size_t)360 * NLAT * 16);   // [16][360][4]

  hipMemsetAsync(S, 0, (size_t)16 * 360 * 4 * sizeof(float), stream);

  dft_kernel<<<16 * 181, 64, 0, stream>>>(pred, targ, wq, GG);

  // triangular grid: lt<22 -> 8*(lt+1) m-tiles, lt==22 -> 180; total 2204
  leg_kernel<<<2204, 256, 0, stream>>>(leg, GG, S);

  loss_kernel<<<1, 256, 0, stream>>>(S, wts, out);
}

// Round 4
// 754.464 us; speedup vs baseline: 1.0348x; 1.0348x over previous
//
#include <hip/hip_runtime.h>
#include <math.h>

#define NLAT 361
#define NLON 720
#define EPSF 1e-7f
#define T0F 8.72664625997164788e-3f   // 2*pi/720

// ---------------------------------------------------------------------------
// Kernel 1: real DFT over longitude with TWO symmetry folds:
//   n <-> 720-n  (even/odd split e[n], o[n])
//   n <-> 360-n  (cos(m(360-n)t0) = (-1)^m cos(mnt0)) -> ep/em, op/om
// so the inner loop runs n = 1..179 only. Thread t (64/wave) owns bins
// m = t, t+64, t+128 and also emits reflected bins 360-m via odd/even-n
// accumulator binning. One wave per latitude row, 4 rows per block.
// Output: GG[m][j][bc] = float4(Fp.re, Fp.im, Ft.re, Ft.im) * (2pi/720)*w[j]
// for m = 0..359 (Nyquist bin 360 is dead downstream).
// ---------------------------------------------------------------------------
__global__ __launch_bounds__(256) void dft_kernel(const float* __restrict__ pred,
                                                  const float* __restrict__ targ,
                                                  const float* __restrict__ wq,
                                                  float4* __restrict__ GG) {
  const int bc = blockIdx.y;
  const int j0 = blockIdx.x * 4;
  const int r  = threadIdx.x >> 6;   // wave id = row within block
  const int t  = threadIdx.x & 63;
  const int j  = j0 + r;

  __shared__ float4 EOa[4][180];   // (ep_P, om_P, ep_T, om_T)  even-m set
  __shared__ float4 EOb[4][180];   // (em_P, op_P, em_T, op_T)  odd-m set
  __shared__ float4 cR[4][2];      // (f0, f360, e180, o180) for P and T

  if (j <= 360) {
    const float* fp = pred + ((size_t)bc * NLAT + j) * NLON;
    const float* ft = targ + ((size_t)bc * NLAT + j) * NLON;
    for (int n = 1 + t; n <= 179; n += 64) {
      float pa = fp[n], pb = fp[720 - n], pc = fp[360 - n], pd = fp[360 + n];
      float ta = ft[n], tb = ft[720 - n], tc = ft[360 - n], td = ft[360 + n];
      float eP = pa + pb, oP = pa - pb, e2P = pc + pd, o2P = pc - pd;
      float eT = ta + tb, oT = ta - tb, e2T = tc + td, o2T = tc - td;
      EOa[r][n] = make_float4(eP + e2P, oP - o2P, eT + e2T, oT - o2T);
      EOb[r][n] = make_float4(eP - e2P, oP + o2P, eT - e2T, oT + o2T);
    }
    if (t == 0) {
      cR[r][0] = make_float4(fp[0], fp[360], fp[180] + fp[540], fp[180] - fp[540]);
      cR[r][1] = make_float4(ft[0], ft[360], ft[180] + ft[540], ft[180] - ft[540]);
    }
  }
  __syncthreads();
  if (j > 360) return;

  const float4* eo = (t & 1) ? EOb[r] : EOa[r];   // pick set by m parity

  // rotators per slot: odd-n chain starts at m*t0, even-n chain at 2m*t0,
  // both step by 2m*t0.
  float rc1[3], rs1[3], rc2[3], rs2[3], stc[3], sts[3];
#pragma unroll
  for (int s = 0; s < 3; ++s) {
    int m = t + 64 * s;
    sincosf(T0F * (float)m, &rs1[s], &rc1[s]);
    sincosf(T0F * (float)(2 * m), &sts[s], &stc[s]);
    rc2[s] = stc[s]; rs2[s] = sts[s];
  }

  float aCoP[3], aSoP[3], aCeP[3], aSeP[3];
  float aCoT[3], aSoT[3], aCeT[3], aSeT[3];
#pragma unroll
  for (int s = 0; s < 3; ++s) {
    aCoP[s] = aSoP[s] = aCeP[s] = aSeP[s] = 0.f;
    aCoT[s] = aSoT[s] = aCeT[s] = aSeT[s] = 0.f;
  }

  for (int k = 1; k <= 89; ++k) {
    float4 X1 = eo[2 * k - 1];
    float4 X2 = eo[2 * k];
#pragma unroll
    for (int s = 0; s < 3; ++s) {
      aCoP[s] = fmaf(X1.x, rc1[s], aCoP[s]);
      aSoP[s] = fmaf(X1.y, rs1[s], aSoP[s]);
      aCoT[s] = fmaf(X1.z, rc1[s], aCoT[s]);
      aSoT[s] = fmaf(X1.w, rs1[s], aSoT[s]);
      aCeP[s] = fmaf(X2.x, rc2[s], aCeP[s]);
      aSeP[s] = fmaf(X2.y, rs2[s], aSeP[s]);
      aCeT[s] = fmaf(X2.z, rc2[s], aCeT[s]);
      aSeT[s] = fmaf(X2.w, rs2[s], aSeT[s]);
      float nc1 = fmaf(rc1[s], stc[s], -(rs1[s] * sts[s]));
      float ns1 = fmaf(rs1[s], stc[s],  (rc1[s] * sts[s]));
      rc1[s] = nc1; rs1[s] = ns1;
      float nc2 = fmaf(rc2[s], stc[s], -(rs2[s] * sts[s]));
      float ns2 = fmaf(rs2[s], stc[s],  (rc2[s] * sts[s]));
      rc2[s] = nc2; rs2[s] = ns2;
    }
  }
  { // tail n = 179 (odd); rc1 now at angle 179*m*t0
    float4 X1 = eo[179];
#pragma unroll
    for (int s = 0; s < 3; ++s) {
      aCoP[s] = fmaf(X1.x, rc1[s], aCoP[s]);
      aSoP[s] = fmaf(X1.y, rs1[s], aSoP[s]);
      aCoT[s] = fmaf(X1.z, rc1[s], aCoT[s]);
      aSoT[s] = fmaf(X1.w, rs1[s], aSoT[s]);
    }
  }

  const float sgn = (t & 1) ? -1.f : 1.f;   // (-1)^m
  const float4 cP = cR[r][0];
  const float4 cT = cR[r][1];
  const float sc = T0F * wq[j];
  const float BP = fmaf(sgn, cP.y, cP.x);   // f0 + (-1)^m f360
  const float BT = fmaf(sgn, cT.y, cT.x);

#pragma unroll
  for (int s = 0; s < 3; ++s) {
    const int m = t + 64 * s;
    if (m > 180) continue;
    const float s2 = (m & 2) ? -1.f : 1.f;
    const float cReP = (m & 1) ? 0.f : s2 * cP.z;   // e180 * cos(m*pi/2)
    const float cReT = (m & 1) ? 0.f : s2 * cT.z;
    const float cImP = (m & 1) ? s2 * cP.w : 0.f;   // o180 * sin(m*pi/2)
    const float cImT = (m & 1) ? s2 * cT.w : 0.f;
    // bin m
    {
      float ReP = BP + aCeP[s] + aCoP[s] + cReP;
      float ImP = -(aSeP[s] + aSoP[s] + cImP);
      float ReT = BT + aCeT[s] + aCoT[s] + cReT;
      float ImT = -(aSeT[s] + aSoT[s] + cImT);
      GG[((size_t)m * NLAT + j) * 16 + bc] =
          make_float4(ReP * sc, ImP * sc, ReT * sc, ImT * sc);
    }
    // reflected bin 360-m (m = 1..179; m=0 -> dead bin 360; m=180 self)
    if (m >= 1 && m <= 179) {
      int m2 = 360 - m;
      float ReP = BP + aCeP[s] - aCoP[s] + cReP;
      float ImP = (aSeP[s] - aSoP[s]) + cImP;
      float ReT = BT + aCeT[s] - aCoT[s] + cReT;
      float ImT = (aSeT[s] - aSoT[s]) + cImT;
      GG[((size_t)m2 * NLAT + j) * 16 + bc] =
          make_float4(ReP * sc, ImP * sc, ReT * sc, ImT * sc);
    }
  }
}

// ---------------------------------------------------------------------------
// Kernel 2: Legendre contraction + triangular PSD/cross-spectrum.
// Block = (m, l-parity, 64-row chunk). Stage parity-folded
//   U[p][bc] = GG[m][p] + (-1)^(par+m) GG[m][360-p]  (p=0..179; U[180]=GG[180])
// into LDS once, then STREAM leg rows from global (each (l,m) row read exactly
// once device-wide) with no barriers in the main loop. Thread = (bc, jl) holds
// 4 rows x 4 accumulators; wave reduces over jl and atomically folds the
// eps-weighted quadratic terms into S[bc][l][4].
// ---------------------------------------------------------------------------
__global__ __launch_bounds__(256) void leg_kernel(const float* __restrict__ leg,
                                                  const float4* __restrict__ GG,
                                                  float* __restrict__ S) {
  const int m   = blockIdx.x >> 1;
  const int par = blockIdx.x & 1;
  const int lstart = m + ((m ^ par) & 1);         // first l >= m with l&1==par
  const int lbase  = lstart + 128 * blockIdx.y;   // 64 rows per chunk (stride 2)
  if (lbase > 359) return;

  __shared__ float4 U[184][16];   // p = 0..183 (181..183 zero-padded)

  const int tid = threadIdx.x;
  const int bc  = tid & 15;
  const int jl  = (tid >> 4) & 3;
  const int w   = tid >> 6;

  const float sgnU = ((m + par) & 1) ? -1.f : 1.f;
  const float4* gm = GG + (size_t)m * NLAT * 16;
  for (int idx = tid; idx < 184 * 16; idx += 256) {
    int p = idx >> 4, b = idx & 15;
    float4 u;
    if (p < 180) {
      float4 A  = gm[p * 16 + b];
      float4 Bv = gm[(360 - p) * 16 + b];
      u = make_float4(fmaf(sgnU, Bv.x, A.x), fmaf(sgnU, Bv.y, A.y),
                      fmaf(sgnU, Bv.z, A.z), fmaf(sgnU, Bv.w, A.w));
    } else if (p == 180) {
      u = gm[180 * 16 + b];
    } else {
      u = make_float4(0.f, 0.f, 0.f, 0.f);
    }
    U[p][b] = u;
  }
  __syncthreads();

  const float ef = (m == 0) ? 1.f : 2.f;

  for (int i = 0; i < 4; ++i) {
    int l0 = lbase + 2 * (i * 16 + w * 4);
    if (l0 > 359) break;   // no barriers below: safe
    int l1 = l0 + 2, l2 = l0 + 4, l3 = l0 + 6;
    // clamp row index into the table (l=360 exists; results discarded later)
    int c1 = l1 > 360 ? 360 : l1, c2 = l2 > 360 ? 360 : l2, c3 = l3 > 360 ? 360 : l3;
    const float* lr0 = leg + ((size_t)l0 * NLAT + m) * NLAT;
    const float* lr1 = leg + ((size_t)c1 * NLAT + m) * NLAT;
    const float* lr2 = leg + ((size_t)c2 * NLAT + m) * NLAT;
    const float* lr3 = leg + ((size_t)c3 * NLAT + m) * NLAT;

    float a[4][4];
#pragma unroll
    for (int rr = 0; rr < 4; ++rr)
#pragma unroll
      for (int c = 0; c < 4; ++c) a[rr][c] = 0.f;

#pragma unroll 2
    for (int tq = 0; tq < 46; ++tq) {
      int jj = 4 * tq + jl;              // 0..183 (181..183 hit zero-pad)
      float4 u = U[jj][bc];
      float g0 = lr0[jj], g1 = lr1[jj], g2 = lr2[jj], g3 = lr3[jj];
      a[0][0] = fmaf(g0, u.x, a[0][0]); a[0][1] = fmaf(g0, u.y, a[0][1]);
      a[0][2] = fmaf(g0, u.z, a[0][2]); a[0][3] = fmaf(g0, u.w, a[0][3]);
      a[1][0] = fmaf(g1, u.x, a[1][0]); a[1][1] = fmaf(g1, u.y, a[1][1]);
      a[1][2] = fmaf(g1, u.z, a[1][2]); a[1][3] = fmaf(g1, u.w, a[1][3]);
      a[2][0] = fmaf(g2, u.x, a[2][0]); a[2][1] = fmaf(g2, u.y, a[2][1]);
      a[2][2] = fmaf(g2, u.z, a[2][2]); a[2][3] = fmaf(g2, u.w, a[2][3]);
      a[3][0] = fmaf(g3, u.x, a[3][0]); a[3][1] = fmaf(g3, u.y, a[3][1]);
      a[3][2] = fmaf(g3, u.z, a[3][2]); a[3][3] = fmaf(g3, u.w, a[3][3]);
    }

    // reduce over jl (lane bits 4,5), then fold quadratics + atomics
#pragma unroll
    for (int rr = 0; rr < 4; ++rr)
#pragma unroll
      for (int c = 0; c < 4; ++c) {
        a[rr][c] += __shfl_xor(a[rr][c], 16);
        a[rr][c] += __shfl_xor(a[rr][c], 32);
      }
    if (jl == 0) {
#pragma unroll
      for (int rr = 0; rr < 4; ++rr) {
        int l = l0 + 2 * rr;
        if (l <= 359) {
          float pr = a[rr][0], pi = a[rr][1], tr = a[rr][2], ti = a[rr][3];
          float* sp = S + ((size_t)bc * 360 + l) * 4;
          atomicAdd(sp + 0, ef * (pr * pr + pi * pi));
          atomicAdd(sp + 1, ef * (tr * tr + ti * ti));
          atomicAdd(sp + 2, ef * (pr * tr + pi * ti));
          atomicAdd(sp + 3, ef * (pr * ti - pi * tr));
        }
      }
    }
  }
}

// ---------------------------------------------------------------------------
// Kernel 3: final loss epilogue + reduction. One block.
// ---------------------------------------------------------------------------
__global__ void loss_kernel(const float* __restrict__ S,
                            const float* __restrict__ wts,
                            float* __restrict__ out) {
  const int tid = threadIdx.x;
  float acc = 0.f;
  for (int i = tid; i < 16 * 360; i += 256) {
    int bc = i / 360;
    const float* sp = S + (size_t)i * 4;
    float pp = sp[0] + EPSF;
    float tp = sp[1] + EPSF;
    float sr = sp[2], si = sp[3];
    float mag   = sqrtf(sr * sr + si * si);
    float denom = sqrtf(pp * tp + EPSF);
    float coh   = mag / (denom + EPSF);
    coh = fminf(fmaxf(coh, 0.f), 1.f);
    float sqp = sqrtf(pp), sqt = sqrtf(tp);
    float amp = (sqp - sqt) * (sqp - sqt);
    float dec = 2.f * fmaxf(pp, tp) * (1.f - coh);
    acc += (amp + dec) * wts[bc & 7];
  }
  __shared__ float red[4];
#pragma unroll
  for (int off = 32; off > 0; off >>= 1) acc += __shfl_xor(acc, off, 64);
  if ((tid & 63) == 0) red[tid >> 6] = acc;
  __syncthreads();
  if (tid == 0) {
    float loss = (red[0] + red[1] + red[2] + red[3]) / (360.f * 16.f);
    out[0] = isnan(loss) ? 1e6f : loss;
  }
}

// ---------------------------------------------------------------------------
extern "C" void kernel_launch(void* const* d_in, const int* in_sizes, int n_in,
                              void* d_out, int out_size, void* d_ws, size_t ws_size,
                              hipStream_t stream) {
  const float* pred = (const float*)d_in[0];   // [2,8,361,720]
  const float* targ = (const float*)d_in[1];   // [2,8,361,720]
  const float* wts  = (const float*)d_in[2];   // [8]
  const float* leg  = (const float*)d_in[3];   // [361,361,361]
  const float* wq   = (const float*)d_in[4];   // [361]
  float* out = (float*)d_out;

  float4* GG = (float4*)d_ws;                            // [360][361][16] float4
  float*  S  = (float*)(GG + (size_t)360 * NLAT * 16);   // [16][360][4]

  hipMemsetAsync(S, 0, (size_t)16 * 360 * 4 * sizeof(float), stream);

  dft_kernel<<<dim3(91, 16), 256, 0, stream>>>(pred, targ, wq, GG);

  // x: 360 m * 2 parity classes; y: 64-row l-chunks (max 3)
  leg_kernel<<<dim3(720, 3), 256, 0, stream>>>(leg, GG, S);

  loss_kernel<<<1, 256, 0, stream>>>(S, wts, out);
}

// Round 5
// 637.200 us; speedup vs baseline: 1.2253x; 1.1840x over previous
//
#include <hip/hip_runtime.h>
#include <math.h>

#define NLAT 361
#define NLON 720
#define EPSF 1e-7f
#define T0F 8.72664625997164788e-3f   // 2*pi/720

// ---------------------------------------------------------------------------
// Kernel 1: real DFT over longitude (UNCHANGED from R4 — held constant this
// round so leg's rewrite is the only variable and dft becomes profiler-visible)
// Output: GG[m][j][bc] = float4(Fp.re, Fp.im, Ft.re, Ft.im) * (2pi/720)*w[j]
// ---------------------------------------------------------------------------
__global__ __launch_bounds__(256) void dft_kernel(const float* __restrict__ pred,
                                                  const float* __restrict__ targ,
                                                  const float* __restrict__ wq,
                                                  float4* __restrict__ GG) {
  const int bc = blockIdx.y;
  const int j0 = blockIdx.x * 4;
  const int r  = threadIdx.x >> 6;   // wave id = row within block
  const int t  = threadIdx.x & 63;
  const int j  = j0 + r;

  __shared__ float4 EOa[4][180];   // even-m set
  __shared__ float4 EOb[4][180];   // odd-m set
  __shared__ float4 cR[4][2];

  if (j <= 360) {
    const float* fp = pred + ((size_t)bc * NLAT + j) * NLON;
    const float* ft = targ + ((size_t)bc * NLAT + j) * NLON;
    for (int n = 1 + t; n <= 179; n += 64) {
      float pa = fp[n], pb = fp[720 - n], pc = fp[360 - n], pd = fp[360 + n];
      float ta = ft[n], tb = ft[720 - n], tc = ft[360 - n], td = ft[360 + n];
      float eP = pa + pb, oP = pa - pb, e2P = pc + pd, o2P = pc - pd;
      float eT = ta + tb, oT = ta - tb, e2T = tc + td, o2T = tc - td;
      EOa[r][n] = make_float4(eP + e2P, oP - o2P, eT + e2T, oT - o2T);
      EOb[r][n] = make_float4(eP - e2P, oP + o2P, eT - e2T, oT + o2T);
    }
    if (t == 0) {
      cR[r][0] = make_float4(fp[0], fp[360], fp[180] + fp[540], fp[180] - fp[540]);
      cR[r][1] = make_float4(ft[0], ft[360], ft[180] + ft[540], ft[180] - ft[540]);
    }
  }
  __syncthreads();
  if (j > 360) return;

  const float4* eo = (t & 1) ? EOb[r] : EOa[r];

  float rc1[3], rs1[3], rc2[3], rs2[3], stc[3], sts[3];
#pragma unroll
  for (int s = 0; s < 3; ++s) {
    int m = t + 64 * s;
    sincosf(T0F * (float)m, &rs1[s], &rc1[s]);
    sincosf(T0F * (float)(2 * m), &sts[s], &stc[s]);
    rc2[s] = stc[s]; rs2[s] = sts[s];
  }

  float aCoP[3], aSoP[3], aCeP[3], aSeP[3];
  float aCoT[3], aSoT[3], aCeT[3], aSeT[3];
#pragma unroll
  for (int s = 0; s < 3; ++s) {
    aCoP[s] = aSoP[s] = aCeP[s] = aSeP[s] = 0.f;
    aCoT[s] = aSoT[s] = aCeT[s] = aSeT[s] = 0.f;
  }

  for (int k = 1; k <= 89; ++k) {
    float4 X1 = eo[2 * k - 1];
    float4 X2 = eo[2 * k];
#pragma unroll
    for (int s = 0; s < 3; ++s) {
      aCoP[s] = fmaf(X1.x, rc1[s], aCoP[s]);
      aSoP[s] = fmaf(X1.y, rs1[s], aSoP[s]);
      aCoT[s] = fmaf(X1.z, rc1[s], aCoT[s]);
      aSoT[s] = fmaf(X1.w, rs1[s], aSoT[s]);
      aCeP[s] = fmaf(X2.x, rc2[s], aCeP[s]);
      aSeP[s] = fmaf(X2.y, rs2[s], aSeP[s]);
      aCeT[s] = fmaf(X2.z, rc2[s], aCeT[s]);
      aSeT[s] = fmaf(X2.w, rs2[s], aSeT[s]);
      float nc1 = fmaf(rc1[s], stc[s], -(rs1[s] * sts[s]));
      float ns1 = fmaf(rs1[s], stc[s],  (rc1[s] * sts[s]));
      rc1[s] = nc1; rs1[s] = ns1;
      float nc2 = fmaf(rc2[s], stc[s], -(rs2[s] * sts[s]));
      float ns2 = fmaf(rs2[s], stc[s],  (rc2[s] * sts[s]));
      rc2[s] = nc2; rs2[s] = ns2;
    }
  }
  {
    float4 X1 = eo[179];
#pragma unroll
    for (int s = 0; s < 3; ++s) {
      aCoP[s] = fmaf(X1.x, rc1[s], aCoP[s]);
      aSoP[s] = fmaf(X1.y, rs1[s], aSoP[s]);
      aCoT[s] = fmaf(X1.z, rc1[s], aCoT[s]);
      aSoT[s] = fmaf(X1.w, rs1[s], aSoT[s]);
    }
  }

  const float sgn = (t & 1) ? -1.f : 1.f;
  const float4 cP = cR[r][0];
  const float4 cT = cR[r][1];
  const float sc = T0F * wq[j];
  const float BP = fmaf(sgn, cP.y, cP.x);
  const float BT = fmaf(sgn, cT.y, cT.x);

#pragma unroll
  for (int s = 0; s < 3; ++s) {
    const int m = t + 64 * s;
    if (m > 180) continue;
    const float s2 = (m & 2) ? -1.f : 1.f;
    const float cReP = (m & 1) ? 0.f : s2 * cP.z;
    const float cReT = (m & 1) ? 0.f : s2 * cT.z;
    const float cImP = (m & 1) ? s2 * cP.w : 0.f;
    const float cImT = (m & 1) ? s2 * cT.w : 0.f;
    {
      float ReP = BP + aCeP[s] + aCoP[s] + cReP;
      float ImP = -(aSeP[s] + aSoP[s] + cImP);
      float ReT = BT + aCeT[s] + aCoT[s] + cReT;
      float ImT = -(aSeT[s] + aSoT[s] + cImT);
      GG[((size_t)m * NLAT + j) * 16 + bc] =
          make_float4(ReP * sc, ImP * sc, ReT * sc, ImT * sc);
    }
    if (m >= 1 && m <= 179) {
      int m2 = 360 - m;
      float ReP = BP + aCeP[s] - aCoP[s] + cReP;
      float ImP = (aSeP[s] - aSoP[s]) + cImP;
      float ReT = BT + aCeT[s] - aCoT[s] + cReT;
      float ImT = (aSeT[s] - aSoT[s]) + cImT;
      GG[((size_t)m2 * NLAT + j) * 16 + bc] =
          make_float4(ReP * sc, ImP * sc, ReT * sc, ImT * sc);
    }
  }
}

// ---------------------------------------------------------------------------
// Kernel 2: Legendre contraction + triangular PSD/cross-spectrum — REWRITTEN
// for coalesced memory shape.
//   Block = (m, l-parity, chunk of 32 rows stride 2). 256 thr = 4 waves.
//   lane n (0..63) <-> spectral component (bc = n>>2, comp = n&3).
//   Wave w owns j-chunk [46w, 46w+46) of j = 0..180.
//   U[46] (parity-folded GG row) in REGISTERS, loaded fully coalesced
//   (64 lanes <-> 64 contiguous floats of GG[m][j]).
//   leg rows staged per-wave to transposed LDS tile (each (l,m) row fetched
//   exactly once device-wide = 47 MB floor); inner loop: 8 broadcast
//   ds_read_b128 + 32 FMA per j, zero barriers, zero global.
//   Cross-wave reduction through reused LDS (2 barriers), quadratics + atomics.
// ---------------------------------------------------------------------------
__global__ __launch_bounds__(256) void leg_kernel(const float* __restrict__ leg,
                                                  const float* __restrict__ GGf,
                                                  float* __restrict__ S) {
  const int m   = blockIdx.x >> 1;
  const int par = blockIdx.x & 1;
  const int lstart = m + ((m ^ par) & 1);        // first l >= m with parity par
  const int lbase  = lstart + 64 * blockIdx.y;   // 32 rows, stride 2
  if (lbase > 359) return;
  const int nrows = min(32, (359 - lbase) / 2 + 1);

  // 32 KB, two lives: Lt[4][46][36] (26.5 KB) during compute, R[4][32][64]
  // (32 KB) during reduction. Per-wave Lt regions overlap other waves' R
  // regions -> barrier between phases.
  __shared__ float smem[8192];

  const int tid  = threadIdx.x;
  const int lane = tid & 63;
  const int w    = tid >> 6;
  const int jc0  = w * 46;          // chunk start; len 46,46,46,43

  // ---- U registers: parity-folded spectral row (coalesced 256B loads) ----
  const float sgnU = ((m + par) & 1) ? -1.f : 1.f;
  const float* gm = GGf + (size_t)m * (NLAT * 64);
  float U[46];
#pragma unroll
  for (int jj = 0; jj < 46; ++jj) {
    int j = jc0 + jj;
    float u;
    if (j < 180)       u = fmaf(sgnU, gm[(360 - j) * 64 + lane], gm[j * 64 + lane]);
    else if (j == 180) u = gm[180 * 64 + lane];
    else               u = 0.f;
    U[jj] = u;
  }

  // ---- stage this wave's leg tile, transposed: Lt[jj][r] ----
  float* Lt = smem + w * (46 * 36);
  {
    const int jg = jc0 + lane;                    // this lane's j within chunk
    const bool jok = (lane < 46) && (jg <= 180);
    const float* rowp = leg + ((size_t)lbase * NLAT + m) * NLAT;
    const size_t rstride = (size_t)2 * NLAT * NLAT;
    for (int r = 0; r < 32; ++r) {
      float v = (jok && r < nrows) ? rowp[jg] : 0.f;
      if (lane < 46) Lt[lane * 36 + r] = v;
      rowp += rstride;
    }
  }
  // Lt is wave-private; in-wave DS ordering suffices (no barrier needed here).

  // ---- main loop: rank-1 accumulate, LDS broadcasts + FMA only ----
  float c[32];
#pragma unroll
  for (int r = 0; r < 32; ++r) c[r] = 0.f;

#pragma unroll 2
  for (int jj = 0; jj < 46; ++jj) {
    const float u = U[jj];
    const float* lrow = Lt + jj * 36;
#pragma unroll
    for (int q = 0; q < 8; ++q) {
      float4 Lq = *(const float4*)(lrow + 4 * q);
      c[4 * q + 0] = fmaf(Lq.x, u, c[4 * q + 0]);
      c[4 * q + 1] = fmaf(Lq.y, u, c[4 * q + 1]);
      c[4 * q + 2] = fmaf(Lq.z, u, c[4 * q + 2]);
      c[4 * q + 3] = fmaf(Lq.w, u, c[4 * q + 3]);
    }
  }

  __syncthreads();            // Lt dead -> smem becomes R[4][32][64]
  float* R = smem;
#pragma unroll
  for (int r = 0; r < 32; ++r) R[(w * 32 + r) * 64 + lane] = c[r];
  __syncthreads();

  // ---- cross-wave reduce + quadratics + atomics ----
  const float ef = (m == 0) ? 1.f : 2.f;
  const int r2 = tid >> 4;          // 0..15
  const int bc = tid & 15;
#pragma unroll
  for (int half = 0; half < 2; ++half) {
    const int rr = r2 + 16 * half;
    if (rr < nrows) {
      float4 v0 = *(const float4*)&R[(0 * 32 + rr) * 64 + bc * 4];
      float4 v1 = *(const float4*)&R[(1 * 32 + rr) * 64 + bc * 4];
      float4 v2 = *(const float4*)&R[(2 * 32 + rr) * 64 + bc * 4];
      float4 v3 = *(const float4*)&R[(3 * 32 + rr) * 64 + bc * 4];
      float pr = v0.x + v1.x + v2.x + v3.x;
      float pi = v0.y + v1.y + v2.y + v3.y;
      float tr = v0.z + v1.z + v2.z + v3.z;
      float ti = v0.w + v1.w + v2.w + v3.w;
      const int l = lbase + 2 * rr;
      float* sp = S + ((size_t)bc * 360 + l) * 4;
      atomicAdd(sp + 0, ef * (pr * pr + pi * pi));
      atomicAdd(sp + 1, ef * (tr * tr + ti * ti));
      atomicAdd(sp + 2, ef * (pr * tr + pi * ti));
      atomicAdd(sp + 3, ef * (pr * ti - pi * tr));
    }
  }
}

// ---------------------------------------------------------------------------
// Kernel 3: final loss epilogue + reduction. One block.
// ---------------------------------------------------------------------------
__global__ void loss_kernel(const float* __restrict__ S,
                            const float* __restrict__ wts,
                            float* __restrict__ out) {
  const int tid = threadIdx.x;
  float acc = 0.f;
  for (int i = tid; i < 16 * 360; i += 256) {
    int bc = i / 360;
    const float* sp = S + (size_t)i * 4;
    float pp = sp[0] + EPSF;
    float tp = sp[1] + EPSF;
    float sr = sp[2], si = sp[3];
    float mag   = sqrtf(sr * sr + si * si);
    float denom = sqrtf(pp * tp + EPSF);
    float coh   = mag / (denom + EPSF);
    coh = fminf(fmaxf(coh, 0.f), 1.f);
    float sqp = sqrtf(pp), sqt = sqrtf(tp);
    float amp = (sqp - sqt) * (sqp - sqt);
    float dec = 2.f * fmaxf(pp, tp) * (1.f - coh);
    acc += (amp + dec) * wts[bc & 7];
  }
  __shared__ float red[4];
#pragma unroll
  for (int off = 32; off > 0; off >>= 1) acc += __shfl_xor(acc, off, 64);
  if ((tid & 63) == 0) red[tid >> 6] = acc;
  __syncthreads();
  if (tid == 0) {
    float loss = (red[0] + red[1] + red[2] + red[3]) / (360.f * 16.f);
    out[0] = isnan(loss) ? 1e6f : loss;
  }
}

// ---------------------------------------------------------------------------
extern "C" void kernel_launch(void* const* d_in, const int* in_sizes, int n_in,
                              void* d_out, int out_size, void* d_ws, size_t ws_size,
                              hipStream_t stream) {
  const float* pred = (const float*)d_in[0];   // [2,8,361,720]
  const float* targ = (const float*)d_in[1];   // [2,8,361,720]
  const float* wts  = (const float*)d_in[2];   // [8]
  const float* leg  = (const float*)d_in[3];   // [361,361,361]
  const float* wq   = (const float*)d_in[4];   // [361]
  float* out = (float*)d_out;

  float4* GG = (float4*)d_ws;                            // [360][361][16] float4
  float*  S  = (float*)(GG + (size_t)360 * NLAT * 16);   // [16][360][4]

  hipMemsetAsync(S, 0, (size_t)16 * 360 * 4 * sizeof(float), stream);

  dft_kernel<<<dim3(91, 16), 256, 0, stream>>>(pred, targ, wq, GG);

  // x: 360 m * 2 parity classes; y: 32-row l-chunks (max 6); extras early-exit
  leg_kernel<<<dim3(720, 6), 256, 0, stream>>>(leg, (const float*)GG, S);

  loss_kernel<<<1, 256, 0, stream>>>(S, wts, out);
}

// Round 6
// 582.829 us; speedup vs baseline: 1.3396x; 1.0933x over previous
//
#include <hip/hip_runtime.h>
#include <math.h>

#define NLAT 361
#define NLON 720
#define EPSF 1e-7f
#define T0F 8.72664625997164788e-3f   // 2*pi/720

// ---------------------------------------------------------------------------
// Kernel 1: real DFT over longitude (byte-identical to R5 — held constant so
// the leg rewrite is the only variable and dft finally shows in the profile).
// Output: GG[m][j][bc] = float4(Fp.re, Fp.im, Ft.re, Ft.im) * (2pi/720)*w[j]
// ---------------------------------------------------------------------------
__global__ __launch_bounds__(256) void dft_kernel(const float* __restrict__ pred,
                                                  const float* __restrict__ targ,
                                                  const float* __restrict__ wq,
                                                  float4* __restrict__ GG) {
  const int bc = blockIdx.y;
  const int j0 = blockIdx.x * 4;
  const int r  = threadIdx.x >> 6;   // wave id = row within block
  const int t  = threadIdx.x & 63;
  const int j  = j0 + r;

  __shared__ float4 EOa[4][180];   // even-m set
  __shared__ float4 EOb[4][180];   // odd-m set
  __shared__ float4 cR[4][2];

  if (j <= 360) {
    const float* fp = pred + ((size_t)bc * NLAT + j) * NLON;
    const float* ft = targ + ((size_t)bc * NLAT + j) * NLON;
    for (int n = 1 + t; n <= 179; n += 64) {
      float pa = fp[n], pb = fp[720 - n], pc = fp[360 - n], pd = fp[360 + n];
      float ta = ft[n], tb = ft[720 - n], tc = ft[360 - n], td = ft[360 + n];
      float eP = pa + pb, oP = pa - pb, e2P = pc + pd, o2P = pc - pd;
      float eT = ta + tb, oT = ta - tb, e2T = tc + td, o2T = tc - td;
      EOa[r][n] = make_float4(eP + e2P, oP - o2P, eT + e2T, oT - o2T);
      EOb[r][n] = make_float4(eP - e2P, oP + o2P, eT - e2T, oT + o2T);
    }
    if (t == 0) {
      cR[r][0] = make_float4(fp[0], fp[360], fp[180] + fp[540], fp[180] - fp[540]);
      cR[r][1] = make_float4(ft[0], ft[360], ft[180] + ft[540], ft[180] - ft[540]);
    }
  }
  __syncthreads();
  if (j > 360) return;

  const float4* eo = (t & 1) ? EOb[r] : EOa[r];

  float rc1[3], rs1[3], rc2[3], rs2[3], stc[3], sts[3];
#pragma unroll
  for (int s = 0; s < 3; ++s) {
    int m = t + 64 * s;
    sincosf(T0F * (float)m, &rs1[s], &rc1[s]);
    sincosf(T0F * (float)(2 * m), &sts[s], &stc[s]);
    rc2[s] = stc[s]; rs2[s] = sts[s];
  }

  float aCoP[3], aSoP[3], aCeP[3], aSeP[3];
  float aCoT[3], aSoT[3], aCeT[3], aSeT[3];
#pragma unroll
  for (int s = 0; s < 3; ++s) {
    aCoP[s] = aSoP[s] = aCeP[s] = aSeP[s] = 0.f;
    aCoT[s] = aSoT[s] = aCeT[s] = aSeT[s] = 0.f;
  }

  for (int k = 1; k <= 89; ++k) {
    float4 X1 = eo[2 * k - 1];
    float4 X2 = eo[2 * k];
#pragma unroll
    for (int s = 0; s < 3; ++s) {
      aCoP[s] = fmaf(X1.x, rc1[s], aCoP[s]);
      aSoP[s] = fmaf(X1.y, rs1[s], aSoP[s]);
      aCoT[s] = fmaf(X1.z, rc1[s], aCoT[s]);
      aSoT[s] = fmaf(X1.w, rs1[s], aSoT[s]);
      aCeP[s] = fmaf(X2.x, rc2[s], aCeP[s]);
      aSeP[s] = fmaf(X2.y, rs2[s], aSeP[s]);
      aCeT[s] = fmaf(X2.z, rc2[s], aCeT[s]);
      aSeT[s] = fmaf(X2.w, rs2[s], aSeT[s]);
      float nc1 = fmaf(rc1[s], stc[s], -(rs1[s] * sts[s]));
      float ns1 = fmaf(rs1[s], stc[s],  (rc1[s] * sts[s]));
      rc1[s] = nc1; rs1[s] = ns1;
      float nc2 = fmaf(rc2[s], stc[s], -(rs2[s] * sts[s]));
      float ns2 = fmaf(rs2[s], stc[s],  (rc2[s] * sts[s]));
      rc2[s] = nc2; rs2[s] = ns2;
    }
  }
  {
    float4 X1 = eo[179];
#pragma unroll
    for (int s = 0; s < 3; ++s) {
      aCoP[s] = fmaf(X1.x, rc1[s], aCoP[s]);
      aSoP[s] = fmaf(X1.y, rs1[s], aSoP[s]);
      aCoT[s] = fmaf(X1.z, rc1[s], aCoT[s]);
      aSoT[s] = fmaf(X1.w, rs1[s], aSoT[s]);
    }
  }

  const float sgn = (t & 1) ? -1.f : 1.f;
  const float4 cP = cR[r][0];
  const float4 cT = cR[r][1];
  const float sc = T0F * wq[j];
  const float BP = fmaf(sgn, cP.y, cP.x);
  const float BT = fmaf(sgn, cT.y, cT.x);

#pragma unroll
  for (int s = 0; s < 3; ++s) {
    const int m = t + 64 * s;
    if (m > 180) continue;
    const float s2 = (m & 2) ? -1.f : 1.f;
    const float cReP = (m & 1) ? 0.f : s2 * cP.z;
    const float cReT = (m & 1) ? 0.f : s2 * cT.z;
    const float cImP = (m & 1) ? s2 * cP.w : 0.f;
    const float cImT = (m & 1) ? s2 * cT.w : 0.f;
    {
      float ReP = BP + aCeP[s] + aCoP[s] + cReP;
      float ImP = -(aSeP[s] + aSoP[s] + cImP);
      float ReT = BT + aCeT[s] + aCoT[s] + cReT;
      float ImT = -(aSeT[s] + aSoT[s] + cImT);
      GG[((size_t)m * NLAT + j) * 16 + bc] =
          make_float4(ReP * sc, ImP * sc, ReT * sc, ImT * sc);
    }
    if (m >= 1 && m <= 179) {
      int m2 = 360 - m;
      float ReP = BP + aCeP[s] - aCoP[s] + cReP;
      float ImP = (aSeP[s] - aSoP[s]) + cImP;
      float ReT = BT + aCeT[s] - aCoT[s] + cReT;
      float ImT = (aSeT[s] - aSoT[s]) + cImT;
      GG[((size_t)m2 * NLAT + j) * 16 + bc] =
          make_float4(ReP * sc, ImP * sc, ReT * sc, ImT * sc);
    }
  }
}

// ---------------------------------------------------------------------------
// Kernel 1.5: in-place parity fold. GG[m] row (361 granules of [16]float4)
// becomes U: granule j (0..180)   = Ue[j] = G[j] + G[360-j]   (j=180: G[180])
//            granule 181+j (j<180) = Uo[j] = G[j] - G[360-j]
// Register-buffered, __syncthreads between all reads and all writes (the
// block owns the whole m-row, so in-place is safe).
// ---------------------------------------------------------------------------
__global__ __launch_bounds__(256) void ufold_kernel(float4* __restrict__ GG) {
  const int m = blockIdx.x;
  float4* RB = GG + (size_t)m * NLAT * 16;
  const int tid = threadIdx.x;
  float4 A[12], B[12];
#pragma unroll
  for (int it = 0; it < 12; ++it) {
    int pp = tid + 256 * it;
    if (pp < 181 * 16) {
      int p = pp >> 4, bc = pp & 15;
      A[it] = RB[p * 16 + bc];
      B[it] = RB[(360 - p) * 16 + bc];
    }
  }
  __syncthreads();
#pragma unroll
  for (int it = 0; it < 12; ++it) {
    int pp = tid + 256 * it;
    if (pp < 181 * 16) {
      int p = pp >> 4, bc = pp & 15;
      float4 a = A[it], b = B[it];
      if (p == 180) {
        RB[180 * 16 + bc] = a;   // shared by both parities
      } else {
        RB[p * 16 + bc] =
            make_float4(a.x + b.x, a.y + b.y, a.z + b.z, a.w + b.w);
        RB[(181 + p) * 16 + bc] =
            make_float4(a.x - b.x, a.y - b.y, a.z - b.z, a.w - b.w);
      }
    }
  }
}

// ---------------------------------------------------------------------------
// Kernel 2: Legendre contraction + triangular PSD/cross-spectrum.
// Block = (m, l-parity, 16-row chunk of stride-2 l's). ~2400 useful blocks.
//   - Us: the needed parity's U row staged 46 KB contiguous+coalesced to LDS.
//   - Lt: 16 leg rows (each read exactly once device-wide), row stride 187
//     (odd -> 4 distinct banks for the 4 row-group reads, conflict-free).
//   - lane = (rg 0..3, bg 0..15): 4 rows x (bc=bg, 4 comps) sub-tile per lane;
//     per j per wave: 1 b128 (16 distinct, 2-way free) + 4 b32 (4 distinct
//     banks) feeding 16 FMAs -> VALU-bound by construction.
//   - waves split j mod 4; cross-wave reduce via LDS reuse; 4 atomics/thread.
// ---------------------------------------------------------------------------
#define LROWS 16
__global__ __launch_bounds__(256) void leg_kernel(const float* __restrict__ leg,
                                                  const float* __restrict__ Uf,
                                                  float* __restrict__ S) {
  const int m   = blockIdx.x >> 1;
  const int par = blockIdx.x & 1;
  const int lstart = m + ((m ^ par) & 1);         // first l >= m, l%2 == par
  if (lstart > 359) return;
  const int rows_total = ((359 - lstart) >> 1) + 1;
  const int r0 = LROWS * blockIdx.y;
  if (r0 >= rows_total) return;
  const int nrows = (rows_total - r0 < LROWS) ? rows_total - r0 : LROWS;
  const int lbase = lstart + 2 * r0;

  __shared__ float smem[14576];     // [0,11584): Us (181*16 float4)
                                    // [11584,14576): Lt (16 rows * 187)
  float4* Us4 = (float4*)smem;
  float*  Lt  = smem + 11584;

  const int tid = threadIdx.x;
  const int sel = (m + par) & 1;    // 0 -> Ue granules, 1 -> Uo granules

  const float4* Usrc = (const float4*)Uf + (size_t)m * NLAT * 16;
  for (int idx = tid; idx < 181 * 16; idx += 256) {
    int j = idx >> 4, bc = idx & 15;
    int g = (sel == 0) ? j : (j < 180 ? 181 + j : 180);
    Us4[idx] = Usrc[g * 16 + bc];
  }
  for (int idx = tid; idx < LROWS * 184; idx += 256) {
    int r = idx / 184, j = idx - r * 184;
    float v = 0.f;
    if (r < nrows && j <= 180) {
      int l = lbase + 2 * r;
      v = leg[((size_t)l * NLAT + m) * NLAT + j];
    }
    if (j < 187) Lt[r * 187 + j] = v;
  }
  __syncthreads();

  const int lane = tid & 63;
  const int w    = tid >> 6;
  const int bg   = lane & 15;       // bc
  const int rg   = lane >> 4;       // row group (4 rows)

  float c[4][4];
#pragma unroll
  for (int q = 0; q < 4; ++q)
#pragma unroll
    for (int cc = 0; cc < 4; ++cc) c[q][cc] = 0.f;

#pragma unroll 2
  for (int j = w; j <= 180; j += 4) {
    float4 u = Us4[j * 16 + bg];
    float L0 = Lt[(rg * 4 + 0) * 187 + j];
    float L1 = Lt[(rg * 4 + 1) * 187 + j];
    float L2 = Lt[(rg * 4 + 2) * 187 + j];
    float L3 = Lt[(rg * 4 + 3) * 187 + j];
    c[0][0] = fmaf(L0, u.x, c[0][0]); c[0][1] = fmaf(L0, u.y, c[0][1]);
    c[0][2] = fmaf(L0, u.z, c[0][2]); c[0][3] = fmaf(L0, u.w, c[0][3]);
    c[1][0] = fmaf(L1, u.x, c[1][0]); c[1][1] = fmaf(L1, u.y, c[1][1]);
    c[1][2] = fmaf(L1, u.z, c[1][2]); c[1][3] = fmaf(L1, u.w, c[1][3]);
    c[2][0] = fmaf(L2, u.x, c[2][0]); c[2][1] = fmaf(L2, u.y, c[2][1]);
    c[2][2] = fmaf(L2, u.z, c[2][2]); c[2][3] = fmaf(L2, u.w, c[2][3]);
    c[3][0] = fmaf(L3, u.x, c[3][0]); c[3][1] = fmaf(L3, u.y, c[3][1]);
    c[3][2] = fmaf(L3, u.z, c[3][2]); c[3][3] = fmaf(L3, u.w, c[3][3]);
  }

  __syncthreads();                  // Us dead -> reuse as R[4][16][68]
  float* R = smem;
#pragma unroll
  for (int q = 0; q < 4; ++q)
#pragma unroll
    for (int cc = 0; cc < 4; ++cc)
      R[w * 1088 + (rg * 4 + q) * 68 + bg * 4 + cc] = c[q][cc];
  __syncthreads();

  const int row = tid >> 4;         // 0..15
  const int bc  = tid & 15;
  if (row < nrows) {
    float4 v0 = *(const float4*)&R[0 * 1088 + row * 68 + bc * 4];
    float4 v1 = *(const float4*)&R[1 * 1088 + row * 68 + bc * 4];
    float4 v2 = *(const float4*)&R[2 * 1088 + row * 68 + bc * 4];
    float4 v3 = *(const float4*)&R[3 * 1088 + row * 68 + bc * 4];
    float pr = v0.x + v1.x + v2.x + v3.x;
    float pi = v0.y + v1.y + v2.y + v3.y;
    float tr = v0.z + v1.z + v2.z + v3.z;
    float ti = v0.w + v1.w + v2.w + v3.w;
    const int l = lbase + 2 * row;
    const float ef = (m == 0) ? 1.f : 2.f;
    float* sp = S + ((size_t)bc * 360 + l) * 4;
    atomicAdd(sp + 0, ef * (pr * pr + pi * pi));
    atomicAdd(sp + 1, ef * (tr * tr + ti * ti));
    atomicAdd(sp + 2, ef * (pr * tr + pi * ti));
    atomicAdd(sp + 3, ef * (pr * ti - pi * tr));
  }
}

// ---------------------------------------------------------------------------
// Kernel 3: final loss epilogue + reduction. One block.
// ---------------------------------------------------------------------------
__global__ void loss_kernel(const float* __restrict__ S,
                            const float* __restrict__ wts,
                            float* __restrict__ out) {
  const int tid = threadIdx.x;
  float acc = 0.f;
  for (int i = tid; i < 16 * 360; i += 256) {
    int bc = i / 360;
    const float* sp = S + (size_t)i * 4;
    float pp = sp[0] + EPSF;
    float tp = sp[1] + EPSF;
    float sr = sp[2], si = sp[3];
    float mag   = sqrtf(sr * sr + si * si);
    float denom = sqrtf(pp * tp + EPSF);
    float coh   = mag / (denom + EPSF);
    coh = fminf(fmaxf(coh, 0.f), 1.f);
    float sqp = sqrtf(pp), sqt = sqrtf(tp);
    float amp = (sqp - sqt) * (sqp - sqt);
    float dec = 2.f * fmaxf(pp, tp) * (1.f - coh);
    acc += (amp + dec) * wts[bc & 7];
  }
  __shared__ float red[4];
#pragma unroll
  for (int off = 32; off > 0; off >>= 1) acc += __shfl_xor(acc, off, 64);
  if ((tid & 63) == 0) red[tid >> 6] = acc;
  __syncthreads();
  if (tid == 0) {
    float loss = (red[0] + red[1] + red[2] + red[3]) / (360.f * 16.f);
    out[0] = isnan(loss) ? 1e6f : loss;
  }
}

// ---------------------------------------------------------------------------
extern "C" void kernel_launch(void* const* d_in, const int* in_sizes, int n_in,
                              void* d_out, int out_size, void* d_ws, size_t ws_size,
                              hipStream_t stream) {
  const float* pred = (const float*)d_in[0];   // [2,8,361,720]
  const float* targ = (const float*)d_in[1];   // [2,8,361,720]
  const float* wts  = (const float*)d_in[2];   // [8]
  const float* leg  = (const float*)d_in[3];   // [361,361,361]
  const float* wq   = (const float*)d_in[4];   // [361]
  float* out = (float*)d_out;

  float4* GG = (float4*)d_ws;                            // [360][361][16] float4
  float*  S  = (float*)(GG + (size_t)360 * NLAT * 16);   // [16][360][4]

  hipMemsetAsync(S, 0, (size_t)16 * 360 * 4 * sizeof(float), stream);

  dft_kernel<<<dim3(91, 16), 256, 0, stream>>>(pred, targ, wq, GG);

  ufold_kernel<<<360, 256, 0, stream>>>(GG);   // GG becomes U, in place

  // x: 360 m * 2 parity classes; y: 16-row chunks (max 12); extras early-exit
  leg_kernel<<<dim3(720, 12), 256, 0, stream>>>(leg, (const float*)GG, S);

  loss_kernel<<<1, 256, 0, stream>>>(S, wts, out);
}